// Round 1
// baseline (436.952 us; speedup 1.0000x reference)
//
#include <hip/hip_runtime.h>
#include <hip/hip_bf16.h>

// S2Conv: x (512,64,121) f32, w (64,64,512) f32, Y (512,121) f32
// out (512,64,1771) f32.
// psi[e,g,i] = sum_n Y[n,i] w[e,g,n] / sqrt(512)
// out[b,g, OFF_l + u*d + m] = (1/8) sum_e psi[e,g,l^2+u] * x[b,e,l^2+m]
//
// Strategy: per-l GEMM  C[p=(g,u), q=(b,m)] = sum_e psiT[p][e] * xT[q][e]
// with both operands pre-transposed to K-contiguous bf16 rows in ws.
// Main kernel: direct global->fragment MFMA loads (no LDS), store-bound.

#define OUTROW 1771
#define OUTB   113344  // 64*1771

typedef __attribute__((ext_vector_type(8))) short bf16x8;
typedef __attribute__((ext_vector_type(4))) float floatx4;

__device__ __constant__ int c_off[11] = {0,1,10,35,84,165,286,455,680,969,1330};
__device__ __constant__ signed char c_ltab[121] = {
  0,
  1,1,1,
  2,2,2,2,2,
  3,3,3,3,3,3,3,
  4,4,4,4,4,4,4,4,4,
  5,5,5,5,5,5,5,5,5,5,5,
  6,6,6,6,6,6,6,6,6,6,6,6,6,
  7,7,7,7,7,7,7,7,7,7,7,7,7,7,7,
  8,8,8,8,8,8,8,8,8,8,8,8,8,8,8,8,8,
  9,9,9,9,9,9,9,9,9,9,9,9,9,9,9,9,9,9,9,
  10,10,10,10,10,10,10,10,10,10,10,10,10,10,10,10,10,10,10,10,10
};

// ---------------------------------------------------------------------------
// Prep: blocks [0,256)  : psi_t[64*l^2 + g*d + u][e] = scale * sum_n w[e,g,n]*Y[n,l^2+u]   (bf16)
//       blocks [256,768): x_t [512*l^2 + b*d + m][e] = x[b,e,l^2+m]                        (bf16)
// ---------------------------------------------------------------------------
__global__ __launch_bounds__(256) void prep_kernel(
    const float* __restrict__ x, const float* __restrict__ w,
    const float* __restrict__ Y,
    __hip_bfloat16* __restrict__ psi_t, __hip_bfloat16* __restrict__ x_t)
{
  __shared__ float smem[7744];   // 31 KB, shared by both branches
  const int t = threadIdx.x;

  if (blockIdx.x < 256) {
    // ---- psi branch: block = (g, e-quarter) ----
    const int g  = blockIdx.x & 63;
    const int e0 = (blockIdx.x >> 6) * 16;
    float* Ych = smem;           // [32][128]
    float* wch = smem + 4096;    // [16][33] (padded pitch)

    const int i4 = t & 31;       // i base = 4*i4  (covers i 0..127)
    const int eq = t >> 5;       // e_loc = 2*eq, 2*eq+1
    float acc[2][4] = {{0.f,0.f,0.f,0.f},{0.f,0.f,0.f,0.f}};

    for (int n0 = 0; n0 < 512; n0 += 32) {
      __syncthreads();
      // stage Y chunk [k][i], zero-pad i>=121
      for (int idx = t; idx < 32*128; idx += 256) {
        int k = idx >> 7, i = idx & 127;
        Ych[k*128 + i] = (i < 121) ? Y[(n0 + k)*121 + i] : 0.f;
      }
      // stage w chunk [e_loc][k] (conflict-free writes: lanes vary k)
      {
        int el = t >> 5, k = t & 31;           // t<512 always
        wch[el*33 + k]        = w[((e0 + el)*64 + g)*512 + n0 + k];
        int el2 = (t + 256) >> 5, k2 = t & 31;
        wch[el2*33 + k2]      = w[((e0 + el2)*64 + g)*512 + n0 + k2];
      }
      __syncthreads();
      #pragma unroll
      for (int k = 0; k < 32; ++k) {
        float4 y = *(const float4*)&Ych[k*128 + 4*i4];
        float w0 = wch[(2*eq)*33 + k];
        float w1 = wch[(2*eq+1)*33 + k];
        acc[0][0] += w0*y.x; acc[0][1] += w0*y.y; acc[0][2] += w0*y.z; acc[0][3] += w0*y.w;
        acc[1][0] += w1*y.x; acc[1][1] += w1*y.y; acc[1][2] += w1*y.z; acc[1][3] += w1*y.w;
      }
    }
    const float scale = 0.00552427172801990267f;  // 1/(8*sqrt(512))
    #pragma unroll
    for (int e2 = 0; e2 < 2; ++e2) {
      int e = e0 + 2*eq + e2;
      #pragma unroll
      for (int ii = 0; ii < 4; ++ii) {
        int i = 4*i4 + ii;
        if (i < 121) {
          int l = c_ltab[i];
          int d = 2*l + 1;
          int row = 64*l*l + g*d + (i - l*l);
          psi_t[row*64 + e] = __float2bfloat16(acc[e2][ii] * scale);
        }
      }
    }
  } else {
    // ---- x transpose branch: one block per b ----
    const int b = blockIdx.x - 256;
    const int i  = t & 127;
    const int e0 = t >> 7;  // 0..1
    for (int e = e0; e < 64; e += 2)
      if (i < 121) smem[e*121 + i] = x[(b*64 + e)*121 + i];
    __syncthreads();
    const int wv = t >> 6, lane = t & 63;
    for (int ii = wv; ii < 121; ii += 4) {
      int l = c_ltab[ii];
      int d = 2*l + 1;
      int row = 512*l*l + b*d + (ii - l*l);
      // stride-121 LDS read: 121 odd -> conflict-free; 128B coalesced store
      x_t[row*64 + lane] = __float2bfloat16(smem[lane*121 + ii]);
    }
  }
}

// ---------------------------------------------------------------------------
// Main: per-l GEMM. Block tile: 64 p-rows x 256 q-cols, K=64.
// 4 waves: wave w owns p-rows [p0+16w, +16), all 256 q.
// Fragments loaded straight from global (K-contiguous bf16 rows), no LDS.
// ---------------------------------------------------------------------------
__global__ __launch_bounds__(256) void conv_kernel(
    const __hip_bfloat16* __restrict__ psi_t,
    const __hip_bfloat16* __restrict__ x_t,
    float* __restrict__ out)
{
  const int bid = blockIdx.x;
  int l = 0;
  #pragma unroll
  for (int ll = 1; ll <= 10; ++ll)
    if (bid >= 2*c_off[ll]) l = ll;
  const int d = 2*l + 1;
  const int r = bid - 2*c_off[l];
  const int qtiles = 2*d;
  const int ptile = r / qtiles;
  const int qtile = r - ptile*qtiles;
  const int p0 = ptile*64, q0 = qtile*256;

  const int t = threadIdx.x;
  const int wv = t >> 6, lane = t & 63;
  const int ln15 = lane & 15, quad = lane >> 4;
  const int pw = p0 + wv*16;

  // A fragments: psi_t row = 64*l^2 + p, 8 bf16 at k-offset quad*8 (+32)
  const ushort* psiRow = (const ushort*)psi_t + (64*l*l + pw + ln15)*64 + quad*8;
  const bf16x8 af0 = *(const bf16x8*)(psiRow);
  const bf16x8 af1 = *(const bf16x8*)(psiRow + 32);

  // per-lane output row offsets for the 4 accumulator rows (p fixed per wave)
  int rowoff[4];
  #pragma unroll
  for (int rr = 0; rr < 4; ++rr) {
    int p  = pw + quad*4 + rr;
    int gg = p / d;
    int uu = p - gg*d;
    rowoff[rr] = gg*OUTROW + uu*d;
  }
  const int offl = c_off[l];
  const ushort* xbase = (const ushort*)x_t + 512*l*l*64 + quad*8;

  #pragma unroll 4
  for (int qq = 0; qq < 16; ++qq) {
    const int q = q0 + qq*16 + ln15;
    const ushort* xr = xbase + q*64;
    bf16x8 bf0 = *(const bf16x8*)(xr);
    bf16x8 bf1 = *(const bf16x8*)(xr + 32);
    floatx4 acc = {0.f, 0.f, 0.f, 0.f};
    acc = __builtin_amdgcn_mfma_f32_16x16x32_bf16(af0, bf0, acc, 0, 0, 0);
    acc = __builtin_amdgcn_mfma_f32_16x16x32_bf16(af1, bf1, acc, 0, 0, 0);
    const int bb = q / d;
    const int mm = q - bb*d;
    const int base = bb*OUTB + offl + mm;
    #pragma unroll
    for (int rr = 0; rr < 4; ++rr)
      out[base + rowoff[rr]] = acc[rr];
  }
}

extern "C" void kernel_launch(void* const* d_in, const int* in_sizes, int n_in,
                              void* d_out, int out_size, void* d_ws, size_t ws_size,
                              hipStream_t stream) {
  const float* x = (const float*)d_in[0];   // 512*64*121
  const float* w = (const float*)d_in[1];   // 64*64*512
  const float* Y = (const float*)d_in[2];   // 512*121
  float* out = (float*)d_out;               // 512*64*1771

  __hip_bfloat16* psi_t = (__hip_bfloat16*)d_ws;                       // 7744*64 bf16 (<1MB)
  __hip_bfloat16* x_t   = (__hip_bfloat16*)((char*)d_ws + (1 << 20));  // 61952*64 bf16 (~7.9MB)

  prep_kernel<<<768, 256, 0, stream>>>(x, w, Y, psi_t, x_t);
  conv_kernel<<<3542, 256, 0, stream>>>(psi_t, x_t, out);
}

// Round 2
// 347.033 us; speedup vs baseline: 1.2591x; 1.2591x over previous
//
#include <hip/hip_runtime.h>
#include <hip/hip_bf16.h>

// S2Conv: x (512,64,121) f32, w (64,64,512) f32, Y (512,121) f32
// out (512,64,1771) f32.
// psi[e,g,i] = sum_n Y[n,i] w[e,g,n] / sqrt(512)
// out[b,g, OFF_l + u*d + m] = (1/8) sum_e psi[e,g,l^2+u] * x[b,e,l^2+m]
//
// Per-l GEMM C[p=(g,u), q=(b,m)] = sum_e psiT[p][e] * xT[q][e], both operands
// pre-transposed to K-contiguous bf16 rows in ws. Main kernel: direct
// global->fragment MFMA loads (no LDS), store-bound.

#define OUTROW 1771
#define OUTB   113344  // 64*1771

typedef __attribute__((ext_vector_type(8))) short bf16x8;
typedef __attribute__((ext_vector_type(4))) float floatx4;

__device__ __constant__ int c_off[11] = {0,1,10,35,84,165,286,455,680,969,1330};
__device__ __constant__ signed char c_ltab[121] = {
  0,
  1,1,1,
  2,2,2,2,2,
  3,3,3,3,3,3,3,
  4,4,4,4,4,4,4,4,4,
  5,5,5,5,5,5,5,5,5,5,5,
  6,6,6,6,6,6,6,6,6,6,6,6,6,
  7,7,7,7,7,7,7,7,7,7,7,7,7,7,7,
  8,8,8,8,8,8,8,8,8,8,8,8,8,8,8,8,8,
  9,9,9,9,9,9,9,9,9,9,9,9,9,9,9,9,9,9,9,
  10,10,10,10,10,10,10,10,10,10,10,10,10,10,10,10,10,10,10,10,10
};

// ---------------------------------------------------------------------------
// Prep: blocks [0,512)   : psi  — block=(g, e-eighth); 4 e per thread.
//       blocks [512,1024): x_t  — one block per b, float4-staged transpose.
// psi_t[64*l^2 + g*d + u][e] = scale * sum_n w[e,g,n]*Y[n,l^2+u]   (bf16)
// x_t [512*l^2 + b*d + m][e] = x[b,e,l^2+m]                        (bf16)
// ---------------------------------------------------------------------------
__global__ __launch_bounds__(256) void prep_kernel(
    const float* __restrict__ x, const float* __restrict__ w,
    const float* __restrict__ Y,
    __hip_bfloat16* __restrict__ psi_t, __hip_bfloat16* __restrict__ x_t)
{
  __shared__ float smem[8256];   // psi: Ych 7744 + wch 512 = 8256 f (33 KB)
  const int t = threadIdx.x;

  if (blockIdx.x < 512) {
    // ---- psi branch: block = (g, e-eighth) ----
    const int g  = blockIdx.x & 63;
    const int e0 = (blockIdx.x >> 6) * 8;     // 8 e per block
    float* Ych = smem;                        // [64 n][121 i] (odd pitch: conflict-free)
    float* wch = smem + 7744;                 // [8 e][64 n]

    const int i  = t & 127;                   // i lane (i>=121 lanes compute garbage, discarded)
    const int es = t >> 7;                    // 0..1 -> 4 e each
    float acc[4] = {0.f, 0.f, 0.f, 0.f};

    for (int n0 = 0; n0 < 512; n0 += 64) {
      __syncthreads();
      // stage Y chunk: 64 rows x 121 = 7744 floats, contiguous -> 1936 float4
      {
        const float4* src = (const float4*)(Y + n0*121);
        float4* dst = (float4*)Ych;
        for (int idx = t; idx < 1936; idx += 256) dst[idx] = src[idx];
      }
      // stage w chunk: 8 e x 64 n = 512 floats (coalesced 256B segments)
      {
        int el = t >> 6, k = t & 63;
        wch[el*64 + k]       = w[((e0 + el    )*64 + g)*512 + n0 + k];
        wch[(el+4)*64 + k]   = w[((e0 + el + 4)*64 + g)*512 + n0 + k];
      }
      __syncthreads();
      #pragma unroll 4
      for (int k = 0; k < 64; ++k) {
        float y = Ych[k*121 + i];             // lane-consecutive, conflict-free
        #pragma unroll
        for (int c = 0; c < 4; ++c)           // wch reads are wave-uniform (broadcast)
          acc[c] += wch[(es*4 + c)*64 + k] * y;
      }
    }
    if (i < 121) {
      const float scale = 0.00552427172801990267f;  // 1/(8*sqrt(512))
      int l = c_ltab[i];
      int d = 2*l + 1;
      int row = 64*l*l + g*d + (i - l*l);
      __hip_bfloat16* dst = psi_t + row*64 + e0 + es*4;
      ushort4 v;
      __hip_bfloat16 h0 = __float2bfloat16(acc[0]*scale);
      __hip_bfloat16 h1 = __float2bfloat16(acc[1]*scale);
      __hip_bfloat16 h2 = __float2bfloat16(acc[2]*scale);
      __hip_bfloat16 h3 = __float2bfloat16(acc[3]*scale);
      v.x = *(unsigned short*)&h0; v.y = *(unsigned short*)&h1;
      v.z = *(unsigned short*)&h2; v.w = *(unsigned short*)&h3;
      *(ushort4*)dst = v;                     // 8B-aligned (e offset multiple of 4)
    }
  } else {
    // ---- x transpose branch: one block per b ----
    const int b = blockIdx.x - 512;
    {
      const float4* src = (const float4*)(x + b*7744);  // 7744 = 64*121, 16B-aligned
      float4* dst = (float4*)smem;                      // smem[e*121 + i]
      for (int idx = t; idx < 1936; idx += 256) dst[idx] = src[idx];
    }
    __syncthreads();
    const int wv = t >> 6, lane = t & 63;
    for (int ii = wv; ii < 121; ii += 4) {
      int l = c_ltab[ii];
      int d = 2*l + 1;
      int row = 512*l*l + b*d + (ii - l*l);
      // stride-121 LDS read: odd -> conflict-free; 128B fully-coalesced store
      x_t[row*64 + lane] = __float2bfloat16(smem[lane*121 + ii]);
    }
  }
}

// ---------------------------------------------------------------------------
// Main: per-l GEMM. Block tile: 64 p-rows x 256 q-cols, K=64.
// Wave w owns p-rows [p0+16w, +16), iterates 16 q-subtiles.
// Fragments loaded straight from global (K-contiguous bf16 rows), no LDS.
// ---------------------------------------------------------------------------
__global__ __launch_bounds__(256) void conv_kernel(
    const __hip_bfloat16* __restrict__ psi_t,
    const __hip_bfloat16* __restrict__ x_t,
    float* __restrict__ out)
{
  const int bid = blockIdx.x;
  int l = 0;
  #pragma unroll
  for (int ll = 1; ll <= 10; ++ll)
    if (bid >= 2*c_off[ll]) l = ll;
  const int d = 2*l + 1;
  const int r = bid - 2*c_off[l];
  const int qtiles = 2*d;
  const int ptile = r / qtiles;
  const int qtile = r - ptile*qtiles;
  const int p0 = ptile*64, q0 = qtile*256;

  const int t = threadIdx.x;
  const int wv = t >> 6, lane = t & 63;
  const int ln15 = lane & 15, quad = lane >> 4;
  const int pw = p0 + wv*16;

  // A fragments: psi_t row = 64*l^2 + p, 8 bf16 at k-offset quad*8 (+32)
  const ushort* psiRow = (const ushort*)psi_t + (64*l*l + pw + ln15)*64 + quad*8;
  const bf16x8 af0 = *(const bf16x8*)(psiRow);
  const bf16x8 af1 = *(const bf16x8*)(psiRow + 32);

  // per-lane output row offsets for the 4 accumulator rows (p fixed per wave)
  int rowoff[4];
  #pragma unroll
  for (int rr = 0; rr < 4; ++rr) {
    int p  = pw + quad*4 + rr;
    int gg = p / d;
    int uu = p - gg*d;
    rowoff[rr] = gg*OUTROW + uu*d;
  }
  const int offl = c_off[l];
  const ushort* xbase = (const ushort*)x_t + 512*l*l*64 + quad*8;

  // incremental div/mod of q by d across qq steps (stepm < d -> one correction)
  const int stepd = 16 / d;
  const int stepm = 16 - stepd*d;
  int qlane = q0 + ln15;
  int bb = qlane / d;
  int mm = qlane - bb*d;

  #pragma unroll 4
  for (int qq = 0; qq < 16; ++qq) {
    const ushort* xr = xbase + (q0 + qq*16 + ln15)*64;
    bf16x8 bf0 = *(const bf16x8*)(xr);
    bf16x8 bf1 = *(const bf16x8*)(xr + 32);
    floatx4 acc = {0.f, 0.f, 0.f, 0.f};
    acc = __builtin_amdgcn_mfma_f32_16x16x32_bf16(af0, bf0, acc, 0, 0, 0);
    acc = __builtin_amdgcn_mfma_f32_16x16x32_bf16(af1, bf1, acc, 0, 0, 0);
    const int base = bb*OUTB + offl + mm;
    #pragma unroll
    for (int rr = 0; rr < 4; ++rr)
      out[base + rowoff[rr]] = acc[rr];
    bb += stepd; mm += stepm;
    if (mm >= d) { mm -= d; ++bb; }
  }
}

extern "C" void kernel_launch(void* const* d_in, const int* in_sizes, int n_in,
                              void* d_out, int out_size, void* d_ws, size_t ws_size,
                              hipStream_t stream) {
  const float* x = (const float*)d_in[0];   // 512*64*121
  const float* w = (const float*)d_in[1];   // 64*64*512
  const float* Y = (const float*)d_in[2];   // 512*121
  float* out = (float*)d_out;               // 512*64*1771

  __hip_bfloat16* psi_t = (__hip_bfloat16*)d_ws;                       // 7744*64 bf16 (<1MB)
  __hip_bfloat16* x_t   = (__hip_bfloat16*)((char*)d_ws + (1 << 20));  // 61952*64 bf16 (~7.9MB)

  prep_kernel<<<1024, 256, 0, stream>>>(x, w, Y, psi_t, x_t);
  conv_kernel<<<3542, 256, 0, stream>>>(psi_t, x_t, out);
}